// Round 10
// baseline (1170.000 us; speedup 1.0000x reference)
//
#include <hip/hip_runtime.h>
#include <hip/hip_fp16.h>
#include <math.h>

#define NB    2
#define NQ    8192
#define NCIN  256
#define NG    4
#define NP    8
#define NGP   32
#define NCIMG 32
#define NCOUT 128
#define NVIEW 6
#define GXD   64
#define GYD   64
#define GZD   4

typedef float f32x4 __attribute__((ext_vector_type(4)));
typedef short s16x8 __attribute__((ext_vector_type(8)));
typedef _Float16 f16x8 __attribute__((ext_vector_type(8)));
typedef unsigned short u16;
typedef unsigned int   u32;

__device__ __forceinline__ u16 bf16_rne(float f) {
    u32 u = __float_as_uint(f);
    u32 r = (u + 0x7FFFu + ((u >> 16) & 1u)) >> 16;
    return (u16)r;
}
__device__ __forceinline__ float bf16_f(u16 h) {
    return __uint_as_float(((u32)h) << 16);
}
__device__ __forceinline__ u16 f16_u(float f) {
    return __half_as_ushort(__float2half(f));
}

// ---------------------------------------------------------------------------
// feature transpose: [B,N,128,H,W] -> [B,G,N,H,W,32]  (fp32)
// ---------------------------------------------------------------------------
__global__ void transpose_feat(const float* __restrict__ src, float* __restrict__ dst,
                               int H, int W)
{
    const int total = NB * NG * NVIEW * H * W * 32;
    for (int i = blockIdx.x * blockDim.x + threadIdx.x; i < total;
         i += gridDim.x * blockDim.x) {
        int c = i & 31;
        int r = i >> 5;
        int x = r % W;  r /= W;
        int y = r % H;  r /= H;
        int n = r % NVIEW; r /= NVIEW;
        int g = r & 3;  r >>= 2;
        int b = r;
        dst[i] = src[(((size_t)(b * NVIEW + n) * 128 + g * 32 + c) * H + y) * W + x];
    }
}

// pts_bev [B,256,64,64] -> channel-last [B,4096,256]
__global__ __launch_bounds__(256) void transpose_pts(const float* __restrict__ src,
                                                     float* __restrict__ dst)
{
    __shared__ float tile[64][65];
    const int tid = blockIdx.x;
    const int b = tid >> 8, rest = tid & 255;
    const int p0 = (rest >> 2) << 6, c0 = (rest & 3) << 6;
    const int t = threadIdx.x;
    for (int i = t; i < 4096; i += 256) {
        const int c = i >> 6, p = i & 63;
        tile[c][p] = src[((size_t)(b * 256 + c0 + c) << 12) + p0 + p];
    }
    __syncthreads();
    for (int i = t; i < 4096; i += 256) {
        const int p = i >> 6, c = i & 63;
        dst[((size_t)(b * 4096) + p0 + p) * 256 + c0 + c] = tile[c][p];
    }
}

// offset/scale weights -> split bf16 [256 col][256 k]; cols 224..255 zero
__global__ void pack_wT_split(const float* __restrict__ w_off,
                              const float* __restrict__ w_sc,
                              u16* __restrict__ wTh, u16* __restrict__ wTl)
{
    int i = blockIdx.x * 256 + threadIdx.x;
    if (i >= 256 * 256) return;
    int col = i >> 8, k = i & 255;
    float v = (col < 96) ? w_off[k * 96 + col]
            : (col < 224 ? w_sc[k * 128 + (col - 96)] : 0.f);
    u16 h = bf16_rne(v);
    wTh[col * 256 + k] = h;
    wTl[col * 256 + k] = bf16_rne(v - bf16_f(h));
}

// w_agg [1024][128] fp32 -> bf16 [co][k]
__global__ void pack_wagT(const float* __restrict__ w_agg, u16* __restrict__ dst)
{
    int i = blockIdx.x * 256 + threadIdx.x;
    if (i >= 128 * 1024) return;
    int co = i >> 10, k = i & 1023;
    dst[i] = bf16_rne(w_agg[k * 128 + co]);
}

// conv weights [CO][CI][3][3] fp32 -> f16 [tap9][CO][CI]
__global__ void pack_conv_w_f16(const float* __restrict__ src, u16* __restrict__ dst,
                                int CI, int CO)
{
    const int N = CO * CI * 9;
    for (int i = blockIdx.x * blockDim.x + threadIdx.x; i < N;
         i += gridDim.x * blockDim.x) {
        int tap = i % 9;
        int r = i / 9;
        int ci = r % CI;
        int co = r / CI;
        dst[((size_t)tap * CO + co) * CI + ci] = f16_u(src[i]);
    }
}

// x0 fp32 (atomic-accumulated) -> f16 plane
__global__ void cvt_x0(const float* __restrict__ x, u16* __restrict__ y)
{
    const int N4 = NB * 4096 * 512 / 4;
    for (int i = blockIdx.x * blockDim.x + threadIdx.x; i < N4;
         i += gridDim.x * blockDim.x) {
        float4 v = reinterpret_cast<const float4*>(x)[i];
        u32 lo = (u32)f16_u(v.x) | ((u32)f16_u(v.y) << 16);
        u32 hi = (u32)f16_u(v.z) | ((u32)f16_u(v.w) << 16);
        reinterpret_cast<uint2*>(y)[i] = make_uint2(lo, hi);
    }
}

// ---------------------------------------------------------------------------
// fused per-query kernel, 8 queries per block, 256 threads.
// gather(split-bf16) -> MFMA offset/scale matmul -> tapgen -> float4 sampling
// (reg-accumulated) -> split-bf16 MFMA agg -> atomic CL scatter.
// LDS ~48 KB (tap tables union s_f buffers) -> 3 blocks/CU.
// ---------------------------------------------------------------------------
__global__ __launch_bounds__(256) void fused_query8(
    const float* __restrict__ pts_cl, const float* __restrict__ l2i,
    const float* __restrict__ qmask,
    const u16* __restrict__ wTh, const u16* __restrict__ wTl,
    const float* __restrict__ b_off, const float* __restrict__ b_sc,
    const u16* __restrict__ wagT, const float* __restrict__ b_agg,
    const int* __restrict__ vxp, const int* __restrict__ vyp, const int* __restrict__ vzp,
    const float* __restrict__ fT,
    float* __restrict__ xout_cl)
{
    const int q0 = blockIdx.x << 3;
    const int b  = q0 >> 13;
    const int t  = threadIdx.x;

    __shared__ __align__(16) u16 s_ph[8][256];   // bf16-hi pts, k-swizzled by q
    __shared__ __align__(16) u16 s_pl[8][256];
    __shared__ float s_off[8][96];
    __shared__ float s_sw[8][128];
    __shared__ float s_l2i[96];
    __shared__ __align__(16) char s_un[32768];   // taps | s_fh/s_fl (phased)
    __shared__ int   s_vx[8], s_vy[8], s_vz[8];
    __shared__ float s_qm[8];

    u32  (*s_toff)[16]  = reinterpret_cast<u32 (*)[16]>(s_un);
    u16  (*s_twgt)[16]  = reinterpret_cast<u16 (*)[16]>(s_un + 16384);
    u16  (*s_fh)[1024]  = reinterpret_cast<u16 (*)[1024]>(s_un);
    u16  (*s_fl)[1024]  = reinterpret_cast<u16 (*)[1024]>(s_un + 16384);

    if (t < 8) {
        s_vx[t] = vxp[q0 + t]; s_vy[t] = vyp[q0 + t]; s_vz[t] = vzp[q0 + t];
        s_qm[t] = qmask[q0 + t];
    }
    if (t < 96) s_l2i[t] = l2i[b * 96 + t];
    __syncthreads();

    // gather 8 query features, split to bf16 hi/lo, k-block swizzle ^q
    {
        const int q = t >> 5, c8 = t & 31;
        const float4* p = reinterpret_cast<const float4*>(
            pts_cl + ((size_t)(b * 4096) + s_vy[q] * 64 + s_vx[q]) * 256 + c8 * 8);
        float4 v0 = p[0], v1 = p[1];
        float v[8] = {v0.x, v0.y, v0.z, v0.w, v1.x, v1.y, v1.z, v1.w};
        union { u16 u[8]; uint4 q4; } H, L;
        #pragma unroll
        for (int j = 0; j < 8; ++j) {
            u16 h = bf16_rne(v[j]);
            H.u[j] = h;
            L.u[j] = bf16_rne(v[j] - bf16_f(h));
        }
        const int kb = c8 ^ q;
        *reinterpret_cast<uint4*>(&s_ph[q][kb * 8]) = H.q4;
        *reinterpret_cast<uint4*>(&s_pl[q][kb * 8]) = L.q4;
    }
    __syncthreads();

    // offset/scale matmul via split-bf16 MFMA: M=8 q (dup rows 8..15), N=256, K=256
    {
        const int wv = t >> 6, l = t & 63;
        const int l15 = l & 15, kg = l >> 4;
        const int qa = l15 & 7;
        f32x4 acc[4];
        #pragma unroll
        for (int nf = 0; nf < 4; ++nf) acc[nf] = (f32x4){0.f, 0.f, 0.f, 0.f};
        #pragma unroll
        for (int ks = 0; ks < 8; ++ks) {
            const int kb = (ks * 4 + kg) ^ qa;
            const s16x8 Ah = *reinterpret_cast<const s16x8*>(&s_ph[qa][kb * 8]);
            const s16x8 Al = *reinterpret_cast<const s16x8*>(&s_pl[qa][kb * 8]);
            #pragma unroll
            for (int nf = 0; nf < 4; ++nf) {
                const int col = wv * 64 + nf * 16 + l15;
                const size_t wo = (size_t)col * 256 + ks * 32 + kg * 8;
                const s16x8 Bh = *reinterpret_cast<const s16x8*>(wTh + wo);
                const s16x8 Bl = *reinterpret_cast<const s16x8*>(wTl + wo);
                acc[nf] = __builtin_amdgcn_mfma_f32_16x16x32_bf16(Ah, Bh, acc[nf], 0, 0, 0);
                acc[nf] = __builtin_amdgcn_mfma_f32_16x16x32_bf16(Ah, Bl, acc[nf], 0, 0, 0);
                acc[nf] = __builtin_amdgcn_mfma_f32_16x16x32_bf16(Al, Bh, acc[nf], 0, 0, 0);
            }
        }
        if (kg < 2) {
            #pragma unroll
            for (int nf = 0; nf < 4; ++nf) {
                const int col = wv * 64 + nf * 16 + l15;
                #pragma unroll
                for (int reg = 0; reg < 4; ++reg) {
                    const int q = kg * 4 + reg;
                    if (col < 96)        s_off[q][col]      = acc[nf][reg] + b_off[col];
                    else if (col < 224)  s_sw[q][col - 96]  = acc[nf][reg] + b_sc[col - 96];
                }
            }
        }
    }
    __syncthreads();

    // one thread per (q,gp): softmax + projection + view select + 16 taps
    {
        const int q = t >> 5, gp = t & 31;
        float a0 = s_sw[q][gp * 4 + 0], a1 = s_sw[q][gp * 4 + 1];
        float a2 = s_sw[q][gp * 4 + 2], a3 = s_sw[q][gp * 4 + 3];
        float m  = fmaxf(fmaxf(a0, a1), fmaxf(a2, a3));
        float e0 = expf(a0 - m), e1 = expf(a1 - m), e2 = expf(a2 - m), e3 = expf(a3 - m);
        float inv = 1.f / (e0 + e1 + e2 + e3);
        const float sw0 = e0 * inv, sw1 = e1 * inv, sw2 = e2 * inv, sw3 = e3 * inv;

        float cx = ((float)s_vx[q] + 0.5f) * 0.6f - 19.2f;
        float cy = ((float)s_vy[q] + 0.5f) * 0.6f - 19.2f;
        float cz = ((float)s_vz[q] + 0.5f) * 0.4f - 1.0f;
        float sx = cx + s_off[q][gp * 3 + 0] * 0.6f;
        float sy = cy + s_off[q][gp * 3 + 1] * 0.6f;
        float sz = cz + s_off[q][gp * 3 + 2] * 0.4f;

        int best = 0; float bu = 0.f, bv = 0.f; bool found = false;
        #pragma unroll
        for (int n = 0; n < NVIEW; ++n) {
            const float* M = &s_l2i[n * 16];
            float px = M[0] * sx + M[1] * sy + M[2]  * sz + M[3];
            float py = M[4] * sx + M[5] * sy + M[6]  * sz + M[7];
            float pz = M[8] * sx + M[9] * sy + M[10] * sz + M[11];
            float homo = fmaxf(pz, 1e-5f);
            float u = px / homo / 704.0f;
            float v = py / homo / 256.0f;
            bool val = (pz > 1e-5f) && (u > 0.f) && (u < 1.f) && (v > 0.f) && (v < 1.f);
            if (n == 0) { bu = u; bv = v; }
            if (val && !found) { found = true; best = n; bu = u; bv = v; }
        }

        const int g = gp >> 3;
        const u32 bgv = (u32)((b * 4 + g) * 6 + best);
        auto tapgen = [&](int lidx, int W, int H, u32 lbase, float swl) {
            float px = fminf(fmaxf(bu * (float)W - 0.5f, -1.0e8f), 1.0e8f);
            float py = fminf(fmaxf(bv * (float)H - 0.5f, -1.0e8f), 1.0e8f);
            float x0f = floorf(px), y0f = floorf(py);
            float wx = px - x0f, wy = py - y0f;
            int x0 = (int)x0f, y0 = (int)y0f;
            const u32 base = lbase + bgv * (u32)(H * W * 32);
            #pragma unroll
            for (int ti = 0; ti < 4; ++ti) {
                int xi = x0 + (ti & 1), yi = y0 + (ti >> 1);
                float bw = ((ti & 1) ? wx : 1.f - wx) * ((ti >> 1) ? wy : 1.f - wy);
                bool ok = ((unsigned)xi < (unsigned)W) && ((unsigned)yi < (unsigned)H);
                u32 off = ok ? (base + ((u32)(yi * W + xi) << 5)) : 0u;
                float wgt = ok ? swl * bw : 0.f;
                s_toff[t][lidx * 4 + ti] = off;
                s_twgt[t][lidx * 4 + ti] = f16_u(wgt);
            }
        };
        tapgen(0, 88, 32, 0u,       sw0);
        tapgen(1, 44, 16, 4325376u, sw1);
        tapgen(2, 22,  8, 5406720u, sw2);
        tapgen(3, 11,  4, 5677056u, sw3);
    }
    __syncthreads();

    // sampling into registers: 8 lanes share a pair, float4 per lane
    f32x4 sacc[8];
    #pragma unroll
    for (int j = 0; j < 8; ++j) {
        const int pair = (j * 256 + t) >> 3, c4 = t & 7;
        const u32* toff = s_toff[pair];
        const u16* twgt = s_twgt[pair];
        f32x4 a = (f32x4){0.f, 0.f, 0.f, 0.f};
        #pragma unroll
        for (int tp = 0; tp < 16; ++tp) {
            const float w = __half2float(__ushort_as_half(twgt[tp]));
            const float4 f = *reinterpret_cast<const float4*>(fT + toff[tp] + c4 * 4);
            a[0] = fmaf(w, f.x, a[0]); a[1] = fmaf(w, f.y, a[1]);
            a[2] = fmaf(w, f.z, a[2]); a[3] = fmaf(w, f.w, a[3]);
        }
        sacc[j] = a;
    }
    __syncthreads();   // all tap-table reads done; union region repurposed

    // write s_fh/s_fl (split bf16, agg k-swizzle ^q)
    #pragma unroll
    for (int j = 0; j < 8; ++j) {
        const int pair = (j * 256 + t) >> 3, c4 = t & 7;
        const int q = pair >> 5, gp = pair & 31;
        const int g = gp >> 3, p = gp & 7;
        const int kb = ((p << 2) + g) * 4 + (c4 >> 1);
        const int off = ((kb ^ q) << 3) + (c4 & 1) * 4;
        u16 h[4], lo[4];
        #pragma unroll
        for (int e = 0; e < 4; ++e) {
            h[e]  = bf16_rne(sacc[j][e]);
            lo[e] = bf16_rne(sacc[j][e] - bf16_f(h[e]));
        }
        *reinterpret_cast<uint2*>(&s_fh[q][off]) =
            make_uint2((u32)h[0] | ((u32)h[1] << 16), (u32)h[2] | ((u32)h[3] << 16));
        *reinterpret_cast<uint2*>(&s_fl[q][off]) =
            make_uint2((u32)lo[0] | ((u32)lo[1] << 16), (u32)lo[2] | ((u32)lo[3] << 16));
    }
    __syncthreads();

    // agg MFMA: M=8 (rows 8..15 duplicate), N=128, K=1024, split bf16 A
    {
        const int wv = t >> 6, l = t & 63;
        const int l15 = l & 15, kg = l >> 4;
        const int qa = l15 & 7;
        f32x4 acc0 = {0.f, 0.f, 0.f, 0.f}, acc1 = {0.f, 0.f, 0.f, 0.f};
        const u16* __restrict__ B0 = wagT + (((wv * 2) * 16 + l15) << 10);
        const u16* __restrict__ B1 = wagT + (((wv * 2 + 1) * 16 + l15) << 10);
        for (int ks = 0; ks < 32; ++ks) {
            const int kk = ((((ks << 2) + kg) ^ qa) << 3);
            const s16x8 Ah = *reinterpret_cast<const s16x8*>(&s_fh[qa][kk]);
            const s16x8 Al = *reinterpret_cast<const s16x8*>(&s_fl[qa][kk]);
            const int ko = (ks << 5) + (kg << 3);
            const s16x8 Bh0 = *reinterpret_cast<const s16x8*>(B0 + ko);
            const s16x8 Bh1 = *reinterpret_cast<const s16x8*>(B1 + ko);
            acc0 = __builtin_amdgcn_mfma_f32_16x16x32_bf16(Ah, Bh0, acc0, 0, 0, 0);
            acc0 = __builtin_amdgcn_mfma_f32_16x16x32_bf16(Al, Bh0, acc0, 0, 0, 0);
            acc1 = __builtin_amdgcn_mfma_f32_16x16x32_bf16(Ah, Bh1, acc1, 0, 0, 0);
            acc1 = __builtin_amdgcn_mfma_f32_16x16x32_bf16(Al, Bh1, acc1, 0, 0, 0);
        }
        if (l < 32) {   // rows 0..7 live in lanes 0..31 (row = kg*4+reg)
            #pragma unroll
            for (int reg = 0; reg < 4; ++reg) {
                const int q = kg * 4 + reg;
                const size_t pbase =
                    ((size_t)(b * 4096) + s_vy[q] * 64 + s_vx[q]) * 512 + s_vz[q];
                const float qm = s_qm[q];
                {
                    const int co = (wv * 2) * 16 + l15;
                    atomicAdd(&xout_cl[pbase + co * 4], (acc0[reg] + b_agg[co]) * qm);
                }
                {
                    const int co = (wv * 2 + 1) * 16 + l15;
                    atomicAdd(&xout_cl[pbase + co * 4], (acc1[reg] + b_agg[co]) * qm);
                }
            }
        }
    }
}

// ---------------------------------------------------------------------------
// 3x3 SAME conv + BN + ReLU, f16 MFMA implicit GEMM, double-buffered LDS.
// Block: 1 output row x 64 px x 64 co; wave w: px [w*16,w*16+16), 4 n-frags.
// A-frags shared across n-frags (MFMA:LDS-read = 4:1, conflict-free layout).
// ---------------------------------------------------------------------------
template<bool LAST>
__global__ __launch_bounds__(256) void conv3x3_f16(
    const u16* __restrict__ xin,   // f16 CL [b][4096][CI]
    const u16* __restrict__ wf,    // f16 [tap9][CO][CI]
    const float* __restrict__ gam, const float* __restrict__ bet,
    u16* __restrict__ yf16, float* __restrict__ ynchw, int CI, int CO)
{
    const int b  = blockIdx.x >> 6;
    const int y0 = blockIdx.x & 63;
    const int co0 = blockIdx.y << 6;
    const int t = threadIdx.x;
    const int wv = t >> 6, l = t & 63;
    const int l15 = l & 15, kg = l >> 4;

    __shared__ __align__(16) u16 lds[2][3 * 66 * 32];

    // precompute this thread's staging slots (<=4 of 792 16B-items)
    const int cnt = (t < 24) ? 4 : 3;
    size_t soff[4]; int loff[4]; bool sval[4];
    #pragma unroll
    for (int k = 0; k < 4; ++k) {
        const int i = t + k * 256;
        const int cb = i & 3, xr = i >> 2;
        const int x = xr % 66, r = xr / 66;
        const int yi = y0 - 1 + r, xi = x - 1;
        sval[k] = ((unsigned)yi < 64u) && ((unsigned)xi < 64u) && (i < 792);
        soff[k] = ((size_t)(b * 4096 + yi * 64 + xi)) * CI + cb * 8;
        loff[k] = (r * 66 + x) * 32 + cb * 8;
    }

    f32x4 acc[4];
    #pragma unroll
    for (int nf = 0; nf < 4; ++nf) acc[nf] = (f32x4){0.f, 0.f, 0.f, 0.f};

    const uint4 Z = make_uint4(0u, 0u, 0u, 0u);
    uint4 st[4];
    #pragma unroll
    for (int k = 0; k < 4; ++k)
        if (k < cnt) st[k] = sval[k] ? *reinterpret_cast<const uint4*>(xin + soff[k]) : Z;
    #pragma unroll
    for (int k = 0; k < 4; ++k)
        if (k < cnt && (t + k * 256) < 792)
            *reinterpret_cast<uint4*>(&lds[0][loff[k]]) = st[k];
    __syncthreads();

    int cur = 0;
    for (int cc = 0; cc < CI; cc += 32) {
        const bool more = (cc + 32 < CI);
        if (more) {
            #pragma unroll
            for (int k = 0; k < 4; ++k)
                if (k < cnt)
                    st[k] = sval[k]
                          ? *reinterpret_cast<const uint4*>(xin + soff[k] + cc + 32) : Z;
        }
        #pragma unroll
        for (int ky = 0; ky < 3; ++ky) {
            #pragma unroll
            for (int kx = 0; kx < 3; ++kx) {
                const f16x8 A = *reinterpret_cast<const f16x8*>(
                    &lds[cur][(ky * 66 + wv * 16 + l15 + kx) * 32 + kg * 8]);
                const int tap = ky * 3 + kx;
                #pragma unroll
                for (int nf = 0; nf < 4; ++nf) {
                    const int co = co0 + nf * 16 + l15;
                    const f16x8 B = *reinterpret_cast<const f16x8*>(
                        wf + ((size_t)tap * CO + co) * CI + cc + kg * 8);
                    acc[nf] = __builtin_amdgcn_mfma_f32_16x16x32_f16(A, B, acc[nf], 0, 0, 0);
                }
            }
        }
        if (more) {
            #pragma unroll
            for (int k = 0; k < 4; ++k)
                if (k < cnt && (t + k * 256) < 792)
                    *reinterpret_cast<uint4*>(&lds[cur ^ 1][loff[k]]) = st[k];
        }
        __syncthreads();
        cur ^= 1;
    }

    const float inv = 0.99999500003749978f;   // 1/sqrt(1+1e-5)
    #pragma unroll
    for (int nf = 0; nf < 4; ++nf) {
        const int co = co0 + nf * 16 + l15;
        const float gsc = gam[co] * inv;
        const float bta = bet[co];
        #pragma unroll
        for (int reg = 0; reg < 4; ++reg) {
            const int px = wv * 16 + kg * 4 + reg;
            const float val = fmaxf(fmaf(acc[nf][reg], gsc, bta), 0.f);
            if (LAST) {
                ynchw[(((size_t)(b * CO + co)) << 12) + y0 * 64 + px] = val;
            } else {
                yf16[((size_t)(b * 4096 + y0 * 64 + px)) * CO + co] = f16_u(val);
            }
        }
    }
}

// ---------------------------------------------------------------------------
extern "C" void kernel_launch(void* const* d_in, const int* in_sizes, int n_in,
                              void* d_out, int out_size, void* d_ws, size_t ws_size,
                              hipStream_t stream)
{
    const float* feat0    = (const float*)d_in[0];
    const float* feat1    = (const float*)d_in[1];
    const float* feat2    = (const float*)d_in[2];
    const float* feat3    = (const float*)d_in[3];
    const float* pts_bev  = (const float*)d_in[4];
    const float* l2i      = (const float*)d_in[5];
    const float* qmask    = (const float*)d_in[6];
    const int*   vox_x    = (const int*)d_in[7];
    const int*   vox_y    = (const int*)d_in[8];
    const int*   vox_z    = (const int*)d_in[9];
    const float* w_off    = (const float*)d_in[10];
    const float* b_off    = (const float*)d_in[11];
    const float* w_sc     = (const float*)d_in[12];
    const float* b_sc     = (const float*)d_in[13];
    const float* w_agg    = (const float*)d_in[14];
    const float* b_agg    = (const float*)d_in[15];
    const float* conv1_w  = (const float*)d_in[16];
    const float* conv2_w  = (const float*)d_in[17];
    const float* conv3_w  = (const float*)d_in[18];
    const float* conv4_w  = (const float*)d_in[19];
    const float* bn1_g    = (const float*)d_in[20];
    const float* bn1_b    = (const float*)d_in[21];
    const float* bn2_g    = (const float*)d_in[22];
    const float* bn2_b    = (const float*)d_in[23];
    const float* bn3_g    = (const float*)d_in[24];
    const float* bn3_b    = (const float*)d_in[25];
    const float* bn4_g    = (const float*)d_in[26];
    const float* bn4_b    = (const float*)d_in[27];

    // ---- workspace layout (bytes), total 52,862,976 (< proven 65,150,976) ----
    // A [0, 22978560)          fT0..3 fp32; after fused: f16 conv weights
    // B [22978560, 39755776)   x0f fp32 (atomic) ; after cvt: x2 f16 (8.4MB)
    // C [39755776, 48144384)   ptsCL fp32 -> x0 f16 -> x3 f16
    // D [48144384, 52338688)   x1 f16
    // E [52338688, 52862976)   wTh + wTl + wagT
    char* wsb = (char*)d_ws;
    float* fT0 = (float*)wsb;
    float* fT1 = fT0 + 4325376;
    float* fT2 = fT1 + 1081344;
    float* fT3 = fT2 + 270336;
    u16* wpk = (u16*)wsb;
    u16* w1f = wpk;             // 1,179,648 u16
    u16* w2f = wpk + 1179648;   // 1,179,648
    u16* w3f = wpk + 2359296;   // 2,359,296
    u16* w4f = wpk + 4718592;   //   589,824
    float* x0f   = (float*)(wsb + 22978560);
    u16*   x2f   = (u16*)(wsb + 22978560);
    float* ptsCL = (float*)(wsb + 39755776);
    u16*   x0h   = (u16*)(wsb + 39755776);
    u16*   x3f   = x0h;
    u16*   x1f   = (u16*)(wsb + 48144384);
    u16*   wTh   = (u16*)(wsb + 52338688);
    u16*   wTl   = (u16*)(wsb + 52469760);
    u16*   wagT  = (u16*)(wsb + 52600832);

    pack_wT_split<<<256, 256, 0, stream>>>(w_off, w_sc, wTh, wTl);
    pack_wagT<<<512, 256, 0, stream>>>(w_agg, wagT);
    transpose_pts<<<512, 256, 0, stream>>>(pts_bev, ptsCL);

    transpose_feat<<<1024, 256, 0, stream>>>(feat0, fT0, 32, 88);
    transpose_feat<<< 512, 256, 0, stream>>>(feat1, fT1, 16, 44);
    transpose_feat<<< 128, 256, 0, stream>>>(feat2, fT2,  8, 22);
    transpose_feat<<<  64, 256, 0, stream>>>(feat3, fT3,  4, 11);

    hipMemsetAsync(x0f, 0, (size_t)4194304 * sizeof(float), stream);

    fused_query8<<<NB * NQ / 8, 256, 0, stream>>>(
        ptsCL, l2i, qmask, wTh, wTl, b_off, b_sc, wagT, b_agg,
        vox_x, vox_y, vox_z, fT0, x0f);

    // features dead -> pack f16 conv weights into region A
    pack_conv_w_f16<<<1024, 256, 0, stream>>>(conv1_w, w1f, 512, 256);
    pack_conv_w_f16<<<1024, 256, 0, stream>>>(conv2_w, w2f, 256, 512);
    pack_conv_w_f16<<<2048, 256, 0, stream>>>(conv3_w, w3f, 512, 512);
    pack_conv_w_f16<<< 512, 256, 0, stream>>>(conv4_w, w4f, 512, 128);

    // ptsCL dead -> x0 f16
    cvt_x0<<<1024, 256, 0, stream>>>(x0f, x0h);

    conv3x3_f16<false><<<dim3(NB * 64, 4), 256, 0, stream>>>(
        x0h, w1f, bn1_g, bn1_b, x1f, nullptr, 512, 256);
    conv3x3_f16<false><<<dim3(NB * 64, 8), 256, 0, stream>>>(
        x1f, w2f, bn2_g, bn2_b, x2f, nullptr, 256, 512);
    conv3x3_f16<false><<<dim3(NB * 64, 8), 256, 0, stream>>>(
        x2f, w3f, bn3_g, bn3_b, x3f, nullptr, 512, 512);
    conv3x3_f16<true><<<dim3(NB * 64, 2), 256, 0, stream>>>(
        x3f, w4f, bn4_g, bn4_b, nullptr, (float*)d_out, 512, 128);
}